// Round 2
// baseline (532.650 us; speedup 1.0000x reference)
//
#include <hip/hip_runtime.h>
#include <hip/hip_bf16.h>

typedef __attribute__((ext_vector_type(8))) short short8;
typedef __attribute__((ext_vector_type(4))) float f32x4;

#define BT 65536      // B*T rows
#define D  512
#define NB 1024       // batches
#define NH 768        // 3*256 hidden

static __device__ __forceinline__ unsigned short f2bf(float f) {
    union { __hip_bfloat16 h; unsigned short u; } cv;
    cv.h = __float2bfloat16(f);
    return cv.u;
}

static __device__ __forceinline__ float gelu(float x) {
    return 0.5f * x * (1.0f + erff(x * 0.70710678118654752f));
}

// byte offset into an LDS tile laid out [rows][64 bf16] with XOR swizzle on 16B chunks
static __device__ __forceinline__ int swz(int row, int ch) {
    return row * 128 + (((ch ^ (row & 7)) & 7) << 4);
}

// ---------------- K0: x fp32 -> bf16 ----------------
__global__ void convert_x(const float* __restrict__ x, unsigned short* __restrict__ xb) {
    size_t i = ((size_t)blockIdx.x * 256 + threadIdx.x) * 4;
    float4 v = *(const float4*)(x + i);
    ushort4 o;
    o.x = f2bf(v.x); o.y = f2bf(v.y); o.z = f2bf(v.z); o.w = f2bf(v.w);
    *(ushort4*)(xb + i) = o;
}

// ---------------- transpose [R][C] f32 -> out[c][r] bf16 (row stride ostride) ----------------
__global__ void transpose_to_bf16(const float* __restrict__ in, unsigned short* __restrict__ out,
                                  int R, int C, int ostride) {
    __shared__ float tile[32][33];
    int r0 = blockIdx.x * 32, c0 = blockIdx.y * 32;
    int tx = threadIdx.x, ty = threadIdx.y; // 32 x 8
    for (int yy = 0; yy < 32; yy += 8)
        tile[ty + yy][tx] = in[(size_t)(r0 + ty + yy) * C + c0 + tx];
    __syncthreads();
    for (int yy = 0; yy < 32; yy += 8)
        out[(size_t)(c0 + ty + yy) * ostride + r0 + tx] = f2bf(tile[tx][ty + yy]);
}

// ---------------- concat small scorer params ----------------
__global__ void prep_cat(const float* b1_0, const float* b1_1, const float* b1_2,
                         const float* W2_0, const float* W2_1, const float* W2_2,
                         const float* b2_0, const float* b2_1, const float* b2_2,
                         float* b1cat, float* W2cat, float* b2cat) {
    int t = threadIdx.x;            // 768 threads
    int s = t >> 8, j = t & 255;
    const float* b1p = (s == 0) ? b1_0 : (s == 1) ? b1_1 : b1_2;
    const float* w2p = (s == 0) ? W2_0 : (s == 1) ? W2_1 : W2_2;
    b1cat[t] = b1p[j];
    W2cat[t] = w2p[j];
    if (t < 3) b2cat[t] = (t == 0 ? b2_0 : t == 1 ? b2_1 : b2_2)[0];
}

// ---------------- K1: scorer GEMM, 64 rows x 256 cols per block, fused GELU+W2 reduce ----------------
__global__ __launch_bounds__(512) void scorer_gemm(
        const unsigned short* __restrict__ xb, const unsigned short* __restrict__ W1T,
        const float* __restrict__ b1cat, const float* __restrict__ W2cat,
        const float* __restrict__ b2cat, float* __restrict__ s_out) {
    __shared__ char ldsA[64 * 128];     // 64 rows x 64 bf16
    __shared__ char ldsB[256 * 128];    // 256 cols x 64 bf16
    __shared__ float red[64 * 4];
    int tid = threadIdx.x, lane = tid & 63, w = tid >> 6;
    int wr = w >> 2, wc = w & 3;
    int sc = blockIdx.y;
    size_t rowbase = (size_t)blockIdx.x * 64;
    const unsigned short* Wt = W1T + (size_t)sc * 256 * 512;   // [256][512]
    f32x4 acc[2][4] = {};
    for (int kt = 0; kt < 8; ++kt) {
        int k0 = kt * 64;
        __syncthreads();
        { int r = tid >> 3, ch = tid & 7;
          *(int4*)(ldsA + swz(r, ch)) = *(const int4*)(xb + (rowbase + r) * 512 + k0 + ch * 8); }
        for (int i = 0; i < 4; ++i) {
            int idx = i * 512 + tid; int r = idx >> 3, ch = idx & 7;
            *(int4*)(ldsB + swz(r, ch)) = *(const int4*)(Wt + (size_t)r * 512 + k0 + ch * 8);
        }
        __syncthreads();
        for (int kk = 0; kk < 2; ++kk) {
            int chunk = kk * 4 + (lane >> 4);
            short8 af[2], bfr[4];
            #pragma unroll
            for (int m = 0; m < 2; ++m)
                af[m] = *(const short8*)(ldsA + swz(wr * 32 + m * 16 + (lane & 15), chunk));
            #pragma unroll
            for (int n = 0; n < 4; ++n)
                bfr[n] = *(const short8*)(ldsB + swz(wc * 64 + n * 16 + (lane & 15), chunk));
            #pragma unroll
            for (int m = 0; m < 2; ++m)
                #pragma unroll
                for (int n = 0; n < 4; ++n)
                    acc[m][n] = __builtin_amdgcn_mfma_f32_16x16x32_bf16(af[m], bfr[n], acc[m][n], 0, 0, 0);
        }
    }
    float b1v[4], w2v[4];
    #pragma unroll
    for (int n = 0; n < 4; ++n) {
        int col = wc * 64 + n * 16 + (lane & 15);
        b1v[n] = b1cat[sc * 256 + col];
        w2v[n] = W2cat[sc * 256 + col];
    }
    #pragma unroll
    for (int m = 0; m < 2; ++m)
        #pragma unroll
        for (int j = 0; j < 4; ++j) {
            float p = 0.f;
            #pragma unroll
            for (int n = 0; n < 4; ++n)
                p += gelu(acc[m][n][j] + b1v[n]) * w2v[n];
            for (int off = 1; off < 16; off <<= 1) p += __shfl_xor(p, off);
            if ((lane & 15) == 0)
                red[(wr * 32 + m * 16 + (lane >> 4) * 4 + j) * 4 + wc] = p;
        }
    __syncthreads();
    if (tid < 64) {
        float sv = red[tid * 4] + red[tid * 4 + 1] + red[tid * 4 + 2] + red[tid * 4 + 3] + b2cat[sc];
        s_out[(size_t)sc * BT + rowbase + tid] = sv;
    }
}

// ---------------- K2: per-batch softmax / group-softmax / gates + pooling ----------------
__global__ __launch_bounds__(256) void pool_kernel(
        const float* __restrict__ x, const float* __restrict__ s_all,
        unsigned short* __restrict__ pooledcat, unsigned short* __restrict__ gx) {
    __shared__ float w0s[64], w1s[64], gts[64];
    int tid = threadIdx.x;
    size_t b = blockIdx.x;
    int w = tid >> 6, lane = tid & 63;
    if (w == 0) {
        float v = s_all[b * 64 + lane];
        float m = v;
        for (int off = 32; off; off >>= 1) m = fmaxf(m, __shfl_xor(m, off));
        float e = expf(v - m);
        float su = e;
        for (int off = 32; off; off >>= 1) su += __shfl_xor(su, off);
        w0s[lane] = e / su;
    } else if (w == 1) {
        float v = s_all[BT + b * 64 + lane];
        float m = v;
        for (int off = 4; off; off >>= 1) m = fmaxf(m, __shfl_xor(m, off));
        float e = expf(v - m);
        float su = e;
        for (int off = 4; off; off >>= 1) su += __shfl_xor(su, off);
        w1s[lane] = e / su;
    } else if (w == 2) {
        float v = s_all[2 * BT + b * 64 + lane];
        gts[lane] = 1.0f / (1.0f + expf(-v));
    }
    __syncthreads();
    for (int half = 0; half < 2; ++half) {
        int c = tid + half * 256;
        float a0 = 0.f, a1 = 0.f;
        #pragma unroll 8
        for (int t = 0; t < 64; ++t) {
            float xv = x[(b * 64 + t) * 512 + c];
            a0 += w0s[t] * xv;
            a1 += w1s[t] * xv;
            gx[(b * 64 + t) * 512 + c] = f2bf(xv * gts[t]);
            if ((t & 7) == 7) {
                pooledcat[(b * 8 + (t >> 3)) * 1024 + 512 + c] = f2bf(a1);
                a1 = 0.f;
            }
        }
        unsigned short p0 = f2bf(a0);
        for (int g = 0; g < 8; ++g) pooledcat[(b * 8 + g) * 1024 + c] = p0;
    }
}

// ---------------- K3: base GEMM [8192,1024]@[1024,512] + bp ----------------
__global__ __launch_bounds__(256) void base_gemm(
        const unsigned short* __restrict__ pooledcat, const unsigned short* __restrict__ WpT,
        const float* __restrict__ bp, float* __restrict__ baseout) {
    __shared__ char ldsA[32 * 128];
    __shared__ char ldsB[512 * 128];
    int tid = threadIdx.x, lane = tid & 63, w = tid >> 6;   // 4 waves: cols w*128, rows 0..31
    size_t rowbase = (size_t)blockIdx.x * 32;
    f32x4 acc[2][8] = {};
    for (int kt = 0; kt < 16; ++kt) {
        int k0 = kt * 64;
        __syncthreads();
        { int r = tid >> 3, ch = tid & 7;
          *(int4*)(ldsA + swz(r, ch)) = *(const int4*)(pooledcat + (rowbase + r) * 1024 + k0 + ch * 8); }
        for (int i = 0; i < 16; ++i) {
            int idx = i * 256 + tid; int r = idx >> 3, ch = idx & 7;
            *(int4*)(ldsB + swz(r, ch)) = *(const int4*)(WpT + (size_t)r * 1536 + k0 + ch * 8);
        }
        __syncthreads();
        for (int kk = 0; kk < 2; ++kk) {
            int chunk = kk * 4 + (lane >> 4);
            short8 af[2], bfr[8];
            #pragma unroll
            for (int m = 0; m < 2; ++m)
                af[m] = *(const short8*)(ldsA + swz(m * 16 + (lane & 15), chunk));
            #pragma unroll
            for (int n = 0; n < 8; ++n)
                bfr[n] = *(const short8*)(ldsB + swz(w * 128 + n * 16 + (lane & 15), chunk));
            #pragma unroll
            for (int m = 0; m < 2; ++m)
                #pragma unroll
                for (int n = 0; n < 8; ++n)
                    acc[m][n] = __builtin_amdgcn_mfma_f32_16x16x32_bf16(af[m], bfr[n], acc[m][n], 0, 0, 0);
        }
    }
    #pragma unroll
    for (int n = 0; n < 8; ++n) {
        int col = w * 128 + n * 16 + (lane & 15);
        float bpv = bp[col];
        #pragma unroll
        for (int m = 0; m < 2; ++m)
            #pragma unroll
            for (int j = 0; j < 4; ++j) {
                int row = m * 16 + (lane >> 4) * 4 + j;
                baseout[(rowbase + row) * 512 + col] = acc[m][n][j] + bpv;
            }
    }
}

// ---------------- K4: final GEMM (gated x @ Wp2) + base + GELU + LayerNorm, fully fused ----------------
__global__ __launch_bounds__(512) void final_gemm_ln(
        const unsigned short* __restrict__ gx, const unsigned short* __restrict__ WpT,
        const float* __restrict__ base, const float* __restrict__ ln_g,
        const float* __restrict__ ln_b, float* __restrict__ out) {
    __shared__ char ldsA[64 * 128];
    __shared__ char ldsB[512 * 128];
    __shared__ float redS[64][4], redQ[64][4], muL[64], rsL[64];
    int tid = threadIdx.x, lane = tid & 63, w = tid >> 6;
    int wr = w >> 2, wc = w & 3;
    size_t b = blockIdx.x;           // one block == one batch (64 rows)
    size_t rowbase = b * 64;
    f32x4 acc[2][8] = {};
    for (int kt = 0; kt < 8; ++kt) {
        int k0 = kt * 64;
        __syncthreads();
        { int r = tid >> 3, ch = tid & 7;
          *(int4*)(ldsA + swz(r, ch)) = *(const int4*)(gx + (rowbase + r) * 512 + k0 + ch * 8); }
        for (int i = 0; i < 8; ++i) {
            int idx = i * 512 + tid; int r = idx >> 3, ch = idx & 7;
            *(int4*)(ldsB + swz(r, ch)) = *(const int4*)(WpT + (size_t)r * 1536 + 1024 + k0 + ch * 8);
        }
        __syncthreads();
        for (int kk = 0; kk < 2; ++kk) {
            int chunk = kk * 4 + (lane >> 4);
            short8 af[2], bfr[8];
            #pragma unroll
            for (int m = 0; m < 2; ++m)
                af[m] = *(const short8*)(ldsA + swz(wr * 32 + m * 16 + (lane & 15), chunk));
            #pragma unroll
            for (int n = 0; n < 8; ++n)
                bfr[n] = *(const short8*)(ldsB + swz(wc * 128 + n * 16 + (lane & 15), chunk));
            #pragma unroll
            for (int m = 0; m < 2; ++m)
                #pragma unroll
                for (int n = 0; n < 8; ++n)
                    acc[m][n] = __builtin_amdgcn_mfma_f32_16x16x32_bf16(af[m], bfr[n], acc[m][n], 0, 0, 0);
        }
    }
    // epilogue: + base, GELU, LayerNorm
    float lngv[8], lnbv[8];
    int cols[8];
    #pragma unroll
    for (int n = 0; n < 8; ++n) {
        int col = wc * 128 + n * 16 + (lane & 15);
        cols[n] = col;
        lngv[n] = ln_g[col];
        lnbv[n] = ln_b[col];
    }
    #pragma unroll
    for (int m = 0; m < 2; ++m) {
        int gi = wr * 4 + m * 2 + ((lane >> 4) >> 1);   // group index = row>>3, j-independent
        #pragma unroll
        for (int n = 0; n < 8; ++n) {
            float bv = base[(b * 8 + gi) * 512 + cols[n]];
            #pragma unroll
            for (int j = 0; j < 4; ++j)
                acc[m][n][j] = gelu(acc[m][n][j] + bv);
        }
    }
    #pragma unroll
    for (int m = 0; m < 2; ++m)
        #pragma unroll
        for (int j = 0; j < 4; ++j) {
            float s = 0.f, q = 0.f;
            #pragma unroll
            for (int n = 0; n < 8; ++n) { float v = acc[m][n][j]; s += v; q += v * v; }
            for (int off = 1; off < 16; off <<= 1) { s += __shfl_xor(s, off); q += __shfl_xor(q, off); }
            if ((lane & 15) == 0) {
                int row = wr * 32 + m * 16 + (lane >> 4) * 4 + j;
                redS[row][wc] = s;
                redQ[row][wc] = q;
            }
        }
    __syncthreads();
    if (tid < 64) {
        float s = redS[tid][0] + redS[tid][1] + redS[tid][2] + redS[tid][3];
        float q = redQ[tid][0] + redQ[tid][1] + redQ[tid][2] + redQ[tid][3];
        float mu = s * (1.0f / 512.0f);
        float var = q * (1.0f / 512.0f) - mu * mu;
        muL[tid] = mu;
        rsL[tid] = rsqrtf(var + 1e-5f);
    }
    __syncthreads();
    #pragma unroll
    for (int m = 0; m < 2; ++m)
        #pragma unroll
        for (int j = 0; j < 4; ++j) {
            int row = wr * 32 + m * 16 + (lane >> 4) * 4 + j;
            float mu = muL[row], rs = rsL[row];
            #pragma unroll
            for (int n = 0; n < 8; ++n)
                out[(rowbase + row) * 512 + cols[n]] = (acc[m][n][j] - mu) * rs * lngv[n] + lnbv[n];
        }
}

extern "C" void kernel_launch(void* const* d_in, const int* in_sizes, int n_in,
                              void* d_out, int out_size, void* d_ws, size_t ws_size,
                              hipStream_t stream) {
    const float* x    = (const float*)d_in[0];
    const float* W1a[3] = { (const float*)d_in[1], (const float*)d_in[5], (const float*)d_in[9] };
    const float* b1a[3] = { (const float*)d_in[2], (const float*)d_in[6], (const float*)d_in[10] };
    const float* W2a[3] = { (const float*)d_in[3], (const float*)d_in[7], (const float*)d_in[11] };
    const float* b2a[3] = { (const float*)d_in[4], (const float*)d_in[8], (const float*)d_in[12] };
    const float* Wp   = (const float*)d_in[13];
    const float* bp   = (const float*)d_in[14];
    const float* ln_g = (const float*)d_in[15];
    const float* ln_b = (const float*)d_in[16];
    float* out = (float*)d_out;

    char* ws = (char*)d_ws;
    size_t off = 0;
    auto carve = [&](size_t bytes) { char* p = ws + off; off += (bytes + 255) & ~(size_t)255; return p; };
    // xb (bf16 x for scorers) is dead after scorer_gemm; gx (gated x) is first
    // written by pool_kernel which runs strictly after -> ALIAS them (saves 67 MB).
    unsigned short* xb        = (unsigned short*)carve((size_t)BT * D * 2);        // 67.1 MB
    unsigned short* gx        = xb;                                                // alias (see above)
    unsigned short* W1T       = (unsigned short*)carve((size_t)NH * D * 2);        // 786 KB
    unsigned short* WpT       = (unsigned short*)carve((size_t)D * 1536 * 2);      // 1.57 MB
    float*          b1cat     = (float*)carve(NH * 4);
    float*          W2cat     = (float*)carve(NH * 4);
    float*          b2cat     = (float*)carve(16);
    float*          s_all     = (float*)carve((size_t)3 * BT * 4);                 // 786 KB
    unsigned short* pooledcat = (unsigned short*)carve((size_t)NB * 8 * 1024 * 2); // 16.8 MB
    float*          base      = (float*)carve((size_t)NB * 8 * 512 * 4);           // 16.8 MB

    // 1. conversions / weight prep
    convert_x<<<32768, 256, 0, stream>>>(x, xb);
    dim3 tb(32, 8);
    for (int s = 0; s < 3; ++s)
        transpose_to_bf16<<<dim3(16, 8), tb, 0, stream>>>(W1a[s], W1T + (size_t)s * 256 * 512, 512, 256, 512);
    transpose_to_bf16<<<dim3(48, 16), tb, 0, stream>>>(Wp, WpT, 1536, 512, 1536);
    prep_cat<<<1, 768, 0, stream>>>(b1a[0], b1a[1], b1a[2], W2a[0], W2a[1], W2a[2],
                                    b2a[0], b2a[1], b2a[2], b1cat, W2cat, b2cat);
    // 2. scorers
    scorer_gemm<<<dim3(1024, 3), 512, 0, stream>>>(xb, W1T, b1cat, W2cat, b2cat, s_all);
    // 3. softmax pooling + gating (reads fp32 x, writes gx over xb)
    pool_kernel<<<1024, 256, 0, stream>>>(x, s_all, pooledcat, gx);
    // 4. base = pooledcat @ Wp[0:1024] + bp
    base_gemm<<<256, 256, 0, stream>>>(pooledcat, WpT, bp, base);
    // 5. final = LN(GELU(base + gx @ Wp[1024:1536]))
    final_gemm_ln<<<1024, 512, 0, stream>>>(gx, WpT, base, ln_g, ln_b, out);
}